// Round 7
// baseline (259.914 us; speedup 1.0000x reference)
//
#include <hip/hip_runtime.h>
#include <hip/hip_bf16.h>
#include <cstdint>
#include <cstddef>

#define LAYERS 3
#define EMB 256
#define NB 4096
#define MAXLEN 50
#define NITEMS 50000

typedef float f32x4 __attribute__((ext_vector_type(4)));
typedef __bf16 bf16x8 __attribute__((ext_vector_type(8)));
typedef unsigned short u16;

static __device__ __forceinline__ u16 f2bf(float f) {
  union { float f; uint32_t u; } v; v.f = f;
  uint32_t r = v.u + 0x7FFFu + ((v.u >> 16) & 1u);
  return (u16)(r >> 16);
}

static __device__ __forceinline__ float bf2f(u16 h) {
  union { uint32_t u; float f; } v; v.u = (uint32_t)h << 16; return v.f;
}

static __device__ __forceinline__ f32x4 bfu4(ushort4 h) {
  f32x4 r; r.x = bf2f(h.x); r.y = bf2f(h.y); r.z = bf2f(h.z); r.w = bf2f(h.w);
  return r;
}

template <typename T> __device__ __forceinline__ T cvt_out(float v);
template <> __device__ __forceinline__ float cvt_out<float>(float v) { return v; }
template <> __device__ __forceinline__ u16 cvt_out<u16>(float v) { return f2bf(v); }

// ---------------- pack to bf16 (row-major) ----------------
__global__ void pack_bf16(const float* __restrict__ in, u16* __restrict__ out, int n4) {
  int i = blockIdx.x * blockDim.x + threadIdx.x;
  if (i < n4) {
    f32x4 v = reinterpret_cast<const f32x4*>(in)[i];
    ushort4 o;
    o.x = f2bf(v.x); o.y = f2bf(v.y); o.z = f2bf(v.z); o.w = f2bf(v.w);
    reinterpret_cast<ushort4*>(out)[i] = o;
  }
}

// ---------------- pack item table to bf16 with leading zero pad row ----------------
// out[(i+1)*EMB ...] = bf16(in[i*EMB ...]); out[0..EMB) = 0
__global__ void pack_emb(const float* __restrict__ in, u16* __restrict__ out, int n4tot) {
  int i = blockIdx.x * blockDim.x + threadIdx.x;
  if (i >= n4tot) return;
  ushort4 o;
  if (i < EMB / 4) {
    o.x = 0; o.y = 0; o.z = 0; o.w = 0;
  } else {
    f32x4 v = reinterpret_cast<const f32x4*>(in)[i - EMB / 4];
    o.x = f2bf(v.x); o.y = f2bf(v.y); o.z = f2bf(v.z); o.w = f2bf(v.w);
  }
  reinterpret_cast<ushort4*>(out)[i] = o;
}

// ---------------- gather + mean pool (1 wave/session, bf16 table, 5-deep MLP) ----------------
__global__ void gather_mean(const u16* __restrict__ ebp, const int* __restrict__ items,
                            const float* __restrict__ slen, float* __restrict__ acc,
                            u16* __restrict__ xb) {
  int w = threadIdx.x >> 6, lane = threadIdx.x & 63;
  int b = blockIdx.x * 4 + w;
  f32x4 s = {0.f, 0.f, 0.f, 0.f};
  const int* it = items + (size_t)b * MAXLEN;
  const int le = lane * 4;
#pragma unroll 2
  for (int l = 0; l < MAXLEN; l += 5) {
    int i0 = it[l], i1 = it[l + 1], i2 = it[l + 2], i3 = it[l + 3], i4 = it[l + 4];
    // pad row 0 is zeros -> unconditional loads, 5 in flight
    ushort4 v0 = *reinterpret_cast<const ushort4*>(ebp + (size_t)i0 * EMB + le);
    ushort4 v1 = *reinterpret_cast<const ushort4*>(ebp + (size_t)i1 * EMB + le);
    ushort4 v2 = *reinterpret_cast<const ushort4*>(ebp + (size_t)i2 * EMB + le);
    ushort4 v3 = *reinterpret_cast<const ushort4*>(ebp + (size_t)i3 * EMB + le);
    ushort4 v4 = *reinterpret_cast<const ushort4*>(ebp + (size_t)i4 * EMB + le);
    s += bfu4(v0) + bfu4(v1) + bfu4(v2) + bfu4(v3) + bfu4(v4);
  }
  float inv = 1.0f / slen[b];
  s *= inv;
  *reinterpret_cast<f32x4*>(acc + (size_t)b * EMB + le) = s;
  ushort4 o; o.x = f2bf(s.x); o.y = f2bf(s.y); o.z = f2bf(s.z); o.w = f2bf(s.w);
  *reinterpret_cast<ushort4*>(xb + (size_t)b * EMB + le) = o;
}

// ---------------- GEMM 128x128: C[M][N] = sum_k Am[m][k]*Bt[n][k], split-K via blockIdx.z ----
template <typename OUT_T, bool SWZ>
__global__ __launch_bounds__(256, 3) void gemm_bt(const u16* __restrict__ Am,
                                                  const u16* __restrict__ Bt,
                                                  OUT_T* __restrict__ C,
                                                  int M, int N, int K, size_t zstride) {
  __shared__ u16 As[128 * 32];
  __shared__ u16 Bs[128 * 32];
  const int tid = threadIdx.x;
  const int lane = tid & 63;
  const int wid = tid >> 6;
  const int wr = wid >> 1, wc = wid & 1;  // 2x2 waves, 64x64 each

  int bx = blockIdx.x, by = blockIdx.y;
  if (SWZ) {
    int nwg = gridDim.x * gridDim.y;
    int bid = by * gridDim.x + bx;
    int cpx = nwg >> 3;
    int sw = (bid & 7) * cpx + (bid >> 3);
    bx = sw % gridDim.x; by = sw / gridDim.x;
  }
  const int row0 = by * 128, col0 = bx * 128;
  const int kslice = K / (int)gridDim.z;
  const int kb = blockIdx.z * kslice, ke = kb + kslice;
  C += (size_t)blockIdx.z * zstride;

  f32x4 acc[4][4];
#pragma unroll
  for (int m = 0; m < 4; m++)
#pragma unroll
    for (int n = 0; n < 4; n++)
#pragma unroll
      for (int j = 0; j < 4; j++) acc[m][n][j] = 0.0f;

  const int lrow = lane & 15;
  const int lko = (lane >> 4) * 8;

  for (int k0 = kb; k0 < ke; k0 += 32) {
#pragma unroll
    for (int inst = 0; inst < 2; inst++) {
      int f = inst * 256 + tid;
      int r = f >> 2, c = (f & 3) * 8;
      const u16* gA = Am + (size_t)(row0 + r) * K + k0 + c;
      const u16* gB = Bt + (size_t)(col0 + r) * K + k0 + c;
      __builtin_amdgcn_global_load_lds(
          (__attribute__((address_space(1))) void*)gA,
          (__attribute__((address_space(3))) void*)(As + (size_t)(inst * 256 + wid * 64) * 8),
          16, 0, 0);
      __builtin_amdgcn_global_load_lds(
          (__attribute__((address_space(1))) void*)gB,
          (__attribute__((address_space(3))) void*)(Bs + (size_t)(inst * 256 + wid * 64) * 8),
          16, 0, 0);
    }
    __syncthreads();

    bf16x8 af[4], bfv[4];
#pragma unroll
    for (int m = 0; m < 4; m++)
      af[m] = *reinterpret_cast<const bf16x8*>(As + (wr * 64 + m * 16 + lrow) * 32 + lko);
#pragma unroll
    for (int n = 0; n < 4; n++)
      bfv[n] = *reinterpret_cast<const bf16x8*>(Bs + (wc * 64 + n * 16 + lrow) * 32 + lko);
#pragma unroll
    for (int m = 0; m < 4; m++)
#pragma unroll
      for (int n = 0; n < 4; n++)
        acc[m][n] = __builtin_amdgcn_mfma_f32_16x16x32_bf16(af[m], bfv[n], acc[m][n], 0, 0, 0);
    __syncthreads();
  }

#pragma unroll
  for (int m = 0; m < 4; m++) {
#pragma unroll
    for (int j = 0; j < 4; j++) {
      int r = row0 + wr * 64 + m * 16 + (lane >> 4) * 4 + j;
      OUT_T* cp = C + (size_t)r * N + col0 + wc * 64 + (lane & 15);
#pragma unroll
      for (int n = 0; n < 4; n++) cp[n * 16] = cvt_out<OUT_T>(acc[m][n][j]);
    }
  }
}

// ---------------- GEMM 64x64 (skinny EMB-sized matmuls, K small) ----------------
__global__ __launch_bounds__(256) void gemm_bt64(const u16* __restrict__ Am,
                                                 const u16* __restrict__ Bt,
                                                 u16* __restrict__ C,
                                                 int M, int N, int K) {
  __shared__ u16 As[64 * 32];
  __shared__ u16 Bs[64 * 32];
  const int tid = threadIdx.x;
  const int lane = tid & 63;
  const int wid = tid >> 6;
  const int wr = wid >> 1, wc = wid & 1;  // 2x2 waves, 32x32 each
  const int row0 = blockIdx.y * 64, col0 = blockIdx.x * 64;

  f32x4 acc[2][2];
#pragma unroll
  for (int m = 0; m < 2; m++)
#pragma unroll
    for (int n = 0; n < 2; n++)
#pragma unroll
      for (int j = 0; j < 4; j++) acc[m][n][j] = 0.0f;

  const int lrow = lane & 15;
  const int lko = (lane >> 4) * 8;

  for (int k0 = 0; k0 < K; k0 += 32) {
    int r = tid >> 2, c = (tid & 3) * 8;
    const u16* gA = Am + (size_t)(row0 + r) * K + k0 + c;
    const u16* gB = Bt + (size_t)(col0 + r) * K + k0 + c;
    __builtin_amdgcn_global_load_lds(
        (__attribute__((address_space(1))) void*)gA,
        (__attribute__((address_space(3))) void*)(As + (size_t)(wid * 64) * 8), 16, 0, 0);
    __builtin_amdgcn_global_load_lds(
        (__attribute__((address_space(1))) void*)gB,
        (__attribute__((address_space(3))) void*)(Bs + (size_t)(wid * 64) * 8), 16, 0, 0);
    __syncthreads();

    bf16x8 af[2], bfv[2];
#pragma unroll
    for (int m = 0; m < 2; m++)
      af[m] = *reinterpret_cast<const bf16x8*>(As + (wr * 32 + m * 16 + lrow) * 32 + lko);
#pragma unroll
    for (int n = 0; n < 2; n++)
      bfv[n] = *reinterpret_cast<const bf16x8*>(Bs + (wc * 32 + n * 16 + lrow) * 32 + lko);
#pragma unroll
    for (int m = 0; m < 2; m++)
#pragma unroll
      for (int n = 0; n < 2; n++)
        acc[m][n] = __builtin_amdgcn_mfma_f32_16x16x32_bf16(af[m], bfv[n], acc[m][n], 0, 0, 0);
    __syncthreads();
  }

#pragma unroll
  for (int m = 0; m < 2; m++) {
#pragma unroll
    for (int j = 0; j < 4; j++) {
      int r = row0 + wr * 32 + m * 16 + (lane >> 4) * 4 + j;
      u16* cp = C + (size_t)r * N + col0 + wc * 32 + (lane & 15);
#pragma unroll
      for (int n = 0; n < 2; n++) cp[n * 16] = f2bf(acc[m][n][j]);
    }
  }
}

// ---------------- sum bf16 split-K partials -> bf16 (for uT) ----------------
__global__ void uredux(const u16* __restrict__ zp, u16* __restrict__ uT,
                       int n4, int nsplit, size_t zstride4) {
  int i = blockIdx.x * blockDim.x + threadIdx.x;
  if (i < n4) {
    f32x4 s = {0.f, 0.f, 0.f, 0.f};
    for (int k = 0; k < nsplit; k++)
      s += bfu4(reinterpret_cast<const ushort4*>(zp)[(size_t)k * zstride4 + i]);
    ushort4 o; o.x = f2bf(s.x); o.y = f2bf(s.y); o.z = f2bf(s.z); o.w = f2bf(s.w);
    reinterpret_cast<ushort4*>(uT)[i] = o;
  }
}

// ---------------- bf16 split-K reduce + row norm + accumulate (+final scale) ----------------
__global__ void norm_acc(const u16* __restrict__ zp, size_t zstride, int nsplit,
                         float* __restrict__ acc, u16* __restrict__ xb,
                         float* __restrict__ outp, int fin) {
  int b = blockIdx.x, t = threadIdx.x;
  size_t i = (size_t)b * EMB + t;
  float v = 0.0f;
  for (int s = 0; s < nsplit; s++) v += bf2f(zp[(size_t)s * zstride + i]);
  float s2 = v * v;
#pragma unroll
  for (int o = 32; o > 0; o >>= 1) s2 += __shfl_down(s2, o, 64);
  __shared__ float ws4[4];
  if ((t & 63) == 0) ws4[t >> 6] = s2;
  __syncthreads();
  float tot = ws4[0] + ws4[1] + ws4[2] + ws4[3];
  float rn = 1.0f / fmaxf(sqrtf(tot), 1e-12f);
  if (fin) {
    outp[i] = (acc[i] + v * rn) * 0.25f;
  } else {
    acc[i] += v * rn;
    xb[i] = f2bf(v);
  }
}

// ---------------- launch ----------------
// Per layer (associativity rewrite: DA@(xW^T) == D@(A@(xW^T)), 3.2x fewer FLOPs):
//   yT[e][b] = sum_f W[e][f] x[b][f]          (gemm_bt64, bf16)
//   uT[e][b] = sum_j yT[e][j] A[b][j]         (gemm_bt splitK=4 bf16 partials -> uredux)
//   z [b][e] = sum_j D[b][j]  uT[e][j]        (gemm_bt splitK=4 bf16 partials)
//   acc += z/||z||_row ; xb = bf16(z)         (norm_acc)
extern "C" void kernel_launch(void* const* d_in, const int* in_sizes, int n_in,
                              void* d_out, int out_size, void* d_ws, size_t ws_size,
                              hipStream_t stream) {
  const float* emb   = (const float*)d_in[0];
  const float* D     = (const float*)d_in[1];
  const float* A     = (const float*)d_in[2];
  const int*   items = (const int*)d_in[3];
  const float* slen  = (const float*)d_in[4];
  const float* w     = (const float*)d_in[5];
  float* out = (float*)d_out;

  // workspace carve (~108 MB)
  char* p = (char*)d_ws;
  u16* Db   = (u16*)p;   p += (size_t)NB * NB * 2;             // 32 MB  bf16 D row-major
  u16* Ab   = (u16*)p;   p += (size_t)NB * NB * 2;             // 32 MB  bf16 A row-major
  u16* zp   = (u16*)p;   p += (size_t)4 * NB * EMB * 2;        // 8 MB   bf16 splitK partials
  float* accf = (float*)p; p += (size_t)NB * EMB * 4;          // 4 MB
  u16* xb   = (u16*)p;   p += (size_t)NB * EMB * 2;            // 2 MB
  u16* yT   = (u16*)p;   p += (size_t)EMB * NB * 2;            // 2 MB
  u16* uT   = (u16*)p;   p += (size_t)EMB * NB * 2;            // 2 MB
  u16* wb   = (u16*)p;   p += (size_t)LAYERS * EMB * EMB * 2;  // 0.4 MB
  u16* ebp  = (u16*)p;   p += (size_t)(NITEMS + 1) * EMB * 2;  // 25.6 MB padded bf16 table

  pack_bf16<<<NB * NB / 4 / 256, 256, 0, stream>>>(D, Db, NB * NB / 4);
  pack_bf16<<<NB * NB / 4 / 256, 256, 0, stream>>>(A, Ab, NB * NB / 4);
  pack_bf16<<<LAYERS * EMB * EMB / 4 / 256, 256, 0, stream>>>(w, wb, LAYERS * EMB * EMB / 4);

  int n4tot = (NITEMS + 1) * EMB / 4;
  pack_emb<<<(n4tot + 255) / 256, 256, 0, stream>>>(emb, ebp, n4tot);

  gather_mean<<<NB / 4, 256, 0, stream>>>(ebp, items, slen, accf, xb);

  for (int i = 0; i < LAYERS; i++) {
    // yT[e][b] = sum_f W[e][f] * x[b][f]
    gemm_bt64<<<dim3(NB / 64, EMB / 64), 256, 0, stream>>>(wb + (size_t)i * EMB * EMB, xb, yT,
                                                           EMB, NB, EMB);
    // uT partials: zp[s][e][b] = partial_j yT[e][j] * A[b][j]   (M=256, N=4096)
    gemm_bt<u16, false><<<dim3(NB / 128, EMB / 128, 4), 256, 0, stream>>>(
        yT, Ab, zp, EMB, NB, NB, (size_t)EMB * NB);
    // uT = bf16(sum partials)
    uredux<<<EMB * NB / 4 / 256, 256, 0, stream>>>(zp, uT, EMB * NB / 4, 4,
                                                   (size_t)EMB * NB / 4);
    // z partials: zp[s][b][e] = partial_j D[b][j] * uT[e][j]    (M=4096, N=256)
    gemm_bt<u16, false><<<dim3(EMB / 128, NB / 128, 4), 256, 0, stream>>>(
        Db, uT, zp, NB, EMB, NB, (size_t)NB * EMB);
    // v = sum partials; acc += v/||v||; xb = bf16(v); final: out = 0.25*(acc+v/||v||)
    norm_acc<<<NB, 256, 0, stream>>>(zp, (size_t)NB * EMB, 4, accf, xb, out, i == LAYERS - 1);
  }
}

// Round 8
// 214.086 us; speedup vs baseline: 1.2141x; 1.2141x over previous
//
#include <hip/hip_runtime.h>
#include <hip/hip_bf16.h>
#include <cstdint>
#include <cstddef>

#define LAYERS 3
#define EMB 256
#define NB 4096
#define MAXLEN 50
#define NITEMS 50000

typedef float f32x4 __attribute__((ext_vector_type(4)));
typedef __bf16 bf16x8 __attribute__((ext_vector_type(8)));
typedef unsigned short u16;

static __device__ __forceinline__ u16 f2bf(float f) {
  union { float f; uint32_t u; } v; v.f = f;
  uint32_t r = v.u + 0x7FFFu + ((v.u >> 16) & 1u);
  return (u16)(r >> 16);
}

static __device__ __forceinline__ float bf2f(u16 h) {
  union { uint32_t u; float f; } v; v.u = (uint32_t)h << 16; return v.f;
}

static __device__ __forceinline__ f32x4 bfu4(ushort4 h) {
  f32x4 r; r.x = bf2f(h.x); r.y = bf2f(h.y); r.z = bf2f(h.z); r.w = bf2f(h.w);
  return r;
}

static __device__ __forceinline__ ushort4 f2bf4(f32x4 v) {
  ushort4 o; o.x = f2bf(v.x); o.y = f2bf(v.y); o.z = f2bf(v.z); o.w = f2bf(v.w);
  return o;
}

template <typename T> __device__ __forceinline__ T cvt_out(float v);
template <> __device__ __forceinline__ float cvt_out<float>(float v) { return v; }
template <> __device__ __forceinline__ u16 cvt_out<u16>(float v) { return f2bf(v); }

#define N4_D (NB * NB / 4)
#define N4_W (LAYERS * EMB * EMB / 4)
#define N4_E ((NITEMS + 1) * EMB / 4)

// ---------------- single grid-stride pack: D, A, w -> bf16; emb -> padded bf16 table ----
__global__ void pack_all(const float* __restrict__ D, const float* __restrict__ A,
                         const float* __restrict__ w, const float* __restrict__ emb,
                         u16* __restrict__ Db, u16* __restrict__ Ab,
                         u16* __restrict__ wb, u16* __restrict__ ebp) {
  const int total = N4_D + N4_D + N4_W + N4_E;
  for (int i = blockIdx.x * blockDim.x + threadIdx.x; i < total;
       i += gridDim.x * blockDim.x) {
    int j = i;
    if (j < N4_D) {
      reinterpret_cast<ushort4*>(Db)[j] = f2bf4(reinterpret_cast<const f32x4*>(D)[j]);
    } else if ((j -= N4_D) < N4_D) {
      reinterpret_cast<ushort4*>(Ab)[j] = f2bf4(reinterpret_cast<const f32x4*>(A)[j]);
    } else if ((j -= N4_D) < N4_W) {
      reinterpret_cast<ushort4*>(wb)[j] = f2bf4(reinterpret_cast<const f32x4*>(w)[j]);
    } else {
      j -= N4_W;
      ushort4 o = {0, 0, 0, 0};
      if (j >= EMB / 4) o = f2bf4(reinterpret_cast<const f32x4*>(emb)[j - EMB / 4]);
      reinterpret_cast<ushort4*>(ebp)[j] = o;
    }
  }
}

// ---------------- gather + mean pool (1 wave/session, bf16 table, 5-deep MLP) ----------------
__global__ void gather_mean(const u16* __restrict__ ebp, const int* __restrict__ items,
                            const float* __restrict__ slen, float* __restrict__ acc,
                            u16* __restrict__ xb) {
  int w = threadIdx.x >> 6, lane = threadIdx.x & 63;
  int b = blockIdx.x * 4 + w;
  f32x4 s = {0.f, 0.f, 0.f, 0.f};
  const int* it = items + (size_t)b * MAXLEN;
  const int le = lane * 4;
#pragma unroll 2
  for (int l = 0; l < MAXLEN; l += 5) {
    int i0 = it[l], i1 = it[l + 1], i2 = it[l + 2], i3 = it[l + 3], i4 = it[l + 4];
    ushort4 v0 = *reinterpret_cast<const ushort4*>(ebp + (size_t)i0 * EMB + le);
    ushort4 v1 = *reinterpret_cast<const ushort4*>(ebp + (size_t)i1 * EMB + le);
    ushort4 v2 = *reinterpret_cast<const ushort4*>(ebp + (size_t)i2 * EMB + le);
    ushort4 v3 = *reinterpret_cast<const ushort4*>(ebp + (size_t)i3 * EMB + le);
    ushort4 v4 = *reinterpret_cast<const ushort4*>(ebp + (size_t)i4 * EMB + le);
    s += bfu4(v0) + bfu4(v1) + bfu4(v2) + bfu4(v3) + bfu4(v4);
  }
  float inv = 1.0f / slen[b];
  s *= inv;
  *reinterpret_cast<f32x4*>(acc + (size_t)b * EMB + le) = s;
  *reinterpret_cast<ushort4*>(xb + (size_t)b * EMB + le) = f2bf4(s);
}

// ---------------- GEMM 128x128, BK=64, XOR-swizzled LDS, split-K via blockIdx.z ----------
// C[M][N] = sum_k Am[m][k]*Bt[n][k]. LDS content[r][c] = global[r][c^(r&7)] (16B chunks),
// achieved with linear LDS dest + inverse-swizzled global source (both-sides rule).
template <typename OUT_T>
__global__ __launch_bounds__(256, 3) void gemm_bt(const u16* __restrict__ Am,
                                                  const u16* __restrict__ Bt,
                                                  OUT_T* __restrict__ C,
                                                  int M, int N, int K, size_t zstride) {
  __shared__ __align__(16) u16 As[128 * 64];
  __shared__ __align__(16) u16 Bs[128 * 64];
  const int tid = threadIdx.x;
  const int lane = tid & 63;
  const int wid = tid >> 6;
  const int wr = wid >> 1, wc = wid & 1;  // 2x2 waves, 64x64 each
  const int row0 = blockIdx.y * 128, col0 = blockIdx.x * 128;
  const int kslice = K / (int)gridDim.z;
  const int kb = blockIdx.z * kslice, ke = kb + kslice;
  C += (size_t)blockIdx.z * zstride;

  f32x4 acc[4][4];
#pragma unroll
  for (int m = 0; m < 4; m++)
#pragma unroll
    for (int n = 0; n < 4; n++)
#pragma unroll
      for (int j = 0; j < 4; j++) acc[m][n][j] = 0.0f;

  const int lrow = lane & 15;
  const int lhi = lane >> 4;                        // 0..3
  const int sw7 = lane & 7;                         // == (read row) & 7
  const int cswz = ((lane & 7) ^ (lane >> 3)) * 8;  // inverse-swizzled source k-offset
  const int srow = wid * 8 + (lane >> 3);           // staging row base (+ i*32)

  for (int k0 = kb; k0 < ke; k0 += 64) {
    // stage 128x64 A and B tiles (16 KB each): 4 x global_load_lds x16B per thread per tile
#pragma unroll
    for (int i = 0; i < 4; i++) {
      int r = i * 32 + srow;
      __builtin_amdgcn_global_load_lds(
          (__attribute__((address_space(1))) void*)(Am + (size_t)(row0 + r) * K + k0 + cswz),
          (__attribute__((address_space(3))) void*)(As + (size_t)(i * 256 + wid * 64) * 8),
          16, 0, 0);
      __builtin_amdgcn_global_load_lds(
          (__attribute__((address_space(1))) void*)(Bt + (size_t)(col0 + r) * K + k0 + cswz),
          (__attribute__((address_space(3))) void*)(Bs + (size_t)(i * 256 + wid * 64) * 8),
          16, 0, 0);
    }
    __syncthreads();

#pragma unroll
    for (int kk = 0; kk < 2; kk++) {
      const int co = ((kk * 4 + lhi) ^ sw7) * 8;
      bf16x8 af[4], bfv[4];
#pragma unroll
      for (int m = 0; m < 4; m++)
        af[m] = *reinterpret_cast<const bf16x8*>(As + (wr * 64 + m * 16 + lrow) * 64 + co);
#pragma unroll
      for (int n = 0; n < 4; n++)
        bfv[n] = *reinterpret_cast<const bf16x8*>(Bs + (wc * 64 + n * 16 + lrow) * 64 + co);
#pragma unroll
      for (int m = 0; m < 4; m++)
#pragma unroll
        for (int n = 0; n < 4; n++)
          acc[m][n] = __builtin_amdgcn_mfma_f32_16x16x32_bf16(af[m], bfv[n], acc[m][n], 0, 0, 0);
    }
    __syncthreads();
  }

#pragma unroll
  for (int m = 0; m < 4; m++) {
#pragma unroll
    for (int j = 0; j < 4; j++) {
      int r = row0 + wr * 64 + m * 16 + lhi * 4 + j;
      OUT_T* cp = C + (size_t)r * N + col0 + wc * 64 + lrow;
#pragma unroll
      for (int n = 0; n < 4; n++) cp[n * 16] = cvt_out<OUT_T>(acc[m][n][j]);
    }
  }
}

// ---------------- GEMM 64x64 (skinny EMB-sized matmul, K=256) ----------------
__global__ __launch_bounds__(256) void gemm_bt64(const u16* __restrict__ Am,
                                                 const u16* __restrict__ Bt,
                                                 u16* __restrict__ C,
                                                 int M, int N, int K) {
  __shared__ u16 As[64 * 32];
  __shared__ u16 Bs[64 * 32];
  const int tid = threadIdx.x;
  const int lane = tid & 63;
  const int wid = tid >> 6;
  const int wr = wid >> 1, wc = wid & 1;  // 2x2 waves, 32x32 each
  const int row0 = blockIdx.y * 64, col0 = blockIdx.x * 64;

  f32x4 acc[2][2];
#pragma unroll
  for (int m = 0; m < 2; m++)
#pragma unroll
    for (int n = 0; n < 2; n++)
#pragma unroll
      for (int j = 0; j < 4; j++) acc[m][n][j] = 0.0f;

  const int lrow = lane & 15;
  const int lko = (lane >> 4) * 8;

  for (int k0 = 0; k0 < K; k0 += 32) {
    int r = tid >> 2, c = (tid & 3) * 8;
    const u16* gA = Am + (size_t)(row0 + r) * K + k0 + c;
    const u16* gB = Bt + (size_t)(col0 + r) * K + k0 + c;
    __builtin_amdgcn_global_load_lds(
        (__attribute__((address_space(1))) void*)gA,
        (__attribute__((address_space(3))) void*)(As + (size_t)(wid * 64) * 8), 16, 0, 0);
    __builtin_amdgcn_global_load_lds(
        (__attribute__((address_space(1))) void*)gB,
        (__attribute__((address_space(3))) void*)(Bs + (size_t)(wid * 64) * 8), 16, 0, 0);
    __syncthreads();

    bf16x8 af[2], bfv[2];
#pragma unroll
    for (int m = 0; m < 2; m++)
      af[m] = *reinterpret_cast<const bf16x8*>(As + (wr * 32 + m * 16 + lrow) * 32 + lko);
#pragma unroll
    for (int n = 0; n < 2; n++)
      bfv[n] = *reinterpret_cast<const bf16x8*>(Bs + (wc * 32 + n * 16 + lrow) * 32 + lko);
#pragma unroll
    for (int m = 0; m < 2; m++)
#pragma unroll
      for (int n = 0; n < 2; n++)
        acc[m][n] = __builtin_amdgcn_mfma_f32_16x16x32_bf16(af[m], bfv[n], acc[m][n], 0, 0, 0);
    __syncthreads();
  }

#pragma unroll
  for (int m = 0; m < 2; m++) {
#pragma unroll
    for (int j = 0; j < 4; j++) {
      int r = row0 + wr * 32 + m * 16 + (lane >> 4) * 4 + j;
      u16* cp = C + (size_t)r * N + col0 + wc * 32 + (lane & 15);
#pragma unroll
      for (int n = 0; n < 2; n++) cp[n * 16] = f2bf(acc[m][n][j]);
    }
  }
}

// ---------------- sum bf16 split-K partials -> bf16 (for uT) ----------------
__global__ void uredux(const u16* __restrict__ zp, u16* __restrict__ uT,
                       int n4, int nsplit, size_t zstride4) {
  int i = blockIdx.x * blockDim.x + threadIdx.x;
  if (i < n4) {
    f32x4 s = {0.f, 0.f, 0.f, 0.f};
    for (int k = 0; k < nsplit; k++)
      s += bfu4(reinterpret_cast<const ushort4*>(zp)[(size_t)k * zstride4 + i]);
    reinterpret_cast<ushort4*>(uT)[i] = f2bf4(s);
  }
}

// ---------------- bf16 split-K reduce + row norm + accumulate (+final scale) ----------------
__global__ void norm_acc(const u16* __restrict__ zp, size_t zstride, int nsplit,
                         float* __restrict__ acc, u16* __restrict__ xb,
                         float* __restrict__ outp, int fin) {
  int b = blockIdx.x, t = threadIdx.x;
  size_t i = (size_t)b * EMB + t;
  float v = 0.0f;
  for (int s = 0; s < nsplit; s++) v += bf2f(zp[(size_t)s * zstride + i]);
  float s2 = v * v;
#pragma unroll
  for (int o = 32; o > 0; o >>= 1) s2 += __shfl_down(s2, o, 64);
  __shared__ float ws4[4];
  if ((t & 63) == 0) ws4[t >> 6] = s2;
  __syncthreads();
  float tot = ws4[0] + ws4[1] + ws4[2] + ws4[3];
  float rn = 1.0f / fmaxf(sqrtf(tot), 1e-12f);
  if (fin) {
    outp[i] = (acc[i] + v * rn) * 0.25f;
  } else {
    acc[i] += v * rn;
    xb[i] = f2bf(v);
  }
}

// ---------------- launch ----------------
// Per layer (associativity rewrite: DA@(xW^T) == D@(A@(xW^T)), 3.2x fewer FLOPs):
//   yT[e][b] = sum_f W[e][f] x[b][f]          (gemm_bt64, bf16)
//   uT[e][b] = sum_j yT[e][j] A[b][j]         (gemm_bt splitK=8 bf16 partials -> uredux)
//   z [b][e] = sum_j D[b][j]  uT[e][j]        (gemm_bt splitK=8 bf16 partials)
//   acc += z/||z||_row ; xb = bf16(z)         (norm_acc)
extern "C" void kernel_launch(void* const* d_in, const int* in_sizes, int n_in,
                              void* d_out, int out_size, void* d_ws, size_t ws_size,
                              hipStream_t stream) {
  const float* emb   = (const float*)d_in[0];
  const float* D     = (const float*)d_in[1];
  const float* A     = (const float*)d_in[2];
  const int*   items = (const int*)d_in[3];
  const float* slen  = (const float*)d_in[4];
  const float* w     = (const float*)d_in[5];
  float* out = (float*)d_out;

  // workspace carve (~100 MB); zp overlays ebp (dead after gather_mean)
  char* p = (char*)d_ws;
  u16* Db   = (u16*)p;   p += (size_t)NB * NB * 2;             // 32 MB
  u16* Ab   = (u16*)p;   p += (size_t)NB * NB * 2;             // 32 MB
  float* accf = (float*)p; p += (size_t)NB * EMB * 4;          // 4 MB
  u16* xb   = (u16*)p;   p += (size_t)NB * EMB * 2;            // 2 MB
  u16* yT   = (u16*)p;   p += (size_t)EMB * NB * 2;            // 2 MB
  u16* uT   = (u16*)p;   p += (size_t)EMB * NB * 2;            // 2 MB
  u16* wb   = (u16*)p;   p += (size_t)LAYERS * EMB * EMB * 2;  // 0.4 MB
  u16* ebp  = (u16*)p;   p += (size_t)(NITEMS + 1) * EMB * 2;  // 25.6 MB
  u16* zp   = ebp;  // 8 x [NB][EMB] bf16 = 16 MB, fits in dead ebp region

  pack_all<<<2048, 256, 0, stream>>>(D, A, w, emb, Db, Ab, wb, ebp);
  gather_mean<<<NB / 4, 256, 0, stream>>>(ebp, items, slen, accf, xb);

  for (int i = 0; i < LAYERS; i++) {
    // yT[e][b] = sum_f W[e][f] * x[b][f]
    gemm_bt64<<<dim3(NB / 64, EMB / 64), 256, 0, stream>>>(wb + (size_t)i * EMB * EMB, xb, yT,
                                                           EMB, NB, EMB);
    // uT partials: zp[s][e][b] = partial_j yT[e][j] * A[b][j]   (M=256, N=4096, 8 K-iters)
    gemm_bt<u16><<<dim3(NB / 128, EMB / 128, 8), 256, 0, stream>>>(
        yT, Ab, zp, EMB, NB, NB, (size_t)EMB * NB);
    // uT = bf16(sum partials)
    uredux<<<EMB * NB / 4 / 256, 256, 0, stream>>>(zp, uT, EMB * NB / 4, 8,
                                                   (size_t)EMB * NB / 4);
    // z partials: zp[s][b][e] = partial_j D[b][j] * uT[e][j]    (M=4096, N=256, 8 K-iters)
    gemm_bt<u16><<<dim3(EMB / 128, NB / 128, 8), 256, 0, stream>>>(
        Db, uT, zp, NB, EMB, NB, (size_t)NB * EMB);
    // v = sum partials; acc += v/||v||; xb = bf16(v); final: out = 0.25*(acc+v/||v||)
    norm_acc<<<NB, 256, 0, stream>>>(zp, (size_t)NB * EMB, 8, accf, xb, out, i == LAYERS - 1);
  }
}